// Round 2
// baseline (141.299 us; speedup 1.0000x reference)
//
#include <hip/hip_runtime.h>

#define B_    16
#define CIN_  128
#define COUT_ 128
#define N_    4096
#define K_    16

typedef __attribute__((ext_vector_type(8))) short bf16x8;  // 8 bf16 = 4 VGPR
typedef __attribute__((ext_vector_type(4))) float f32x4;
typedef __attribute__((ext_vector_type(4))) int   i32x4;

__device__ inline unsigned short f2bf(float f) {  // round-to-nearest-even
  unsigned u = __float_as_uint(f);
  u += 0x7fffu + ((u >> 16) & 1u);
  return (unsigned short)(u >> 16);
}

// Monotonic per-group barrier counters (group = blocks sharing l&7 = one XCD
// under round-robin dispatch). Never reset; each launch consumes one epoch of
// exactly 64 increments per group: target = (base & ~63) + 64.
__device__ int g_bar[8 * 32];

// ---------------------------------------------------------------------------
// Fused kernel, occupancy-doubled: 512 blocks x 1024 thr, LDS 71.7 KB
// => 2 blocks/CU (143.4 KB LDS, 2048 thr, VGPR forced <=64 by
// __launch_bounds__(1024,8)); grid == 2*CUs => all co-resident => spin
// barrier deadlock-free. While one resident block sits in a barrier/drain/
// spin, the other issues work: phase-transition latency is now hidden.
// Phase 1: 128n x 128co tile; 16 waves = 8 n-slices x 2 co-halves.
// Phase 2: 2 units x 512 thr, each the proven 16-lane-row gather at 64n.
// ---------------------------------------------------------------------------
__global__ __launch_bounds__(1024, 8) void fused_k(
    const float* __restrict__ W, const float* __restrict__ x,
    const int* __restrict__ ei, const float* __restrict__ bias,
    float* __restrict__ out, unsigned short* __restrict__ h) {
  __shared__ unsigned short Wl[128 * 136];                 // [co][ci]+8 pad, 34.8 KB
  __shared__ __align__(16) unsigned short He[128 * 144];   // [n][co]+16 pad, 36.9 KB
                                                           // (aliased by idxs in ph2)
  const int tid  = threadIdx.x;
  const int l    = blockIdx.x;          // 0..511
  const int j    = l & 7;               // group / XCD under round-robin
  const int slot = l >> 3;              // 0..63
  const int b    = (j << 1) | (slot >> 5);
  const int n0   = (slot & 31) * 128;

  const int lane = tid & 63;
  const int w    = tid >> 6;            // wave 0..15
  const int wn   = w & 7;               // n slice [n0+16*wn, +16)
  const int wg   = w >> 3;              // co half [64*wg, +64)
  const int m    = lane & 15;
  const int quad = lane >> 4;

  // ---- phase 0: stage W fp32 -> bf16 -> LDS (identical RTE conversion) ----
#pragma unroll
  for (int r = 0; r < 2; ++r) {
    int id  = tid + 1024 * r;      // 0..2047 segments of 8 floats
    int co  = id >> 4;
    int seg = id & 15;
    const float4* wp = reinterpret_cast<const float4*>(W + co * CIN_ + 8 * seg);
    float4 v0 = wp[0];
    float4 v1 = wp[1];
    unsigned p0 = (unsigned)f2bf(v0.x) | ((unsigned)f2bf(v0.y) << 16);
    unsigned p1 = (unsigned)f2bf(v0.z) | ((unsigned)f2bf(v0.w) << 16);
    unsigned p2 = (unsigned)f2bf(v1.x) | ((unsigned)f2bf(v1.y) << 16);
    unsigned p3 = (unsigned)f2bf(v1.z) | ((unsigned)f2bf(v1.w) << 16);
    *reinterpret_cast<uint4*>(&Wl[co * 136 + 8 * seg]) =
        make_uint4(p0, p1, p2, p3);
  }

  // ---- A-fragments from global (independent of LDS staging; loads overlap
  //      the staging above, conversion overlaps the staging latency) ----
  const float* xb = x + (size_t)b * CIN_ * N_ + n0 + 16 * wn + m;
  bf16x8 a[4];
#pragma unroll
  for (int s = 0; s < 4; ++s)
#pragma unroll
    for (int t = 0; t < 8; ++t)
      a[s][t] = (short)f2bf(xb[(size_t)(32 * s + 8 * quad + t) * N_]);

  __syncthreads();

  // ---- phase 1: MFMA gemm + ReLU, epilogue transpose through He ----
  const int nrow = 16 * wn + 4 * quad;   // block-local n of c[0]
#pragma unroll
  for (int t = 0; t < 4; ++t) {   // 4 co-tiles of 16 within this wave's half
    f32x4 c = {0.f, 0.f, 0.f, 0.f};
#pragma unroll
    for (int s = 0; s < 4; ++s) { // K = 4 x 32
      bf16x8 bf = *reinterpret_cast<const bf16x8*>(
          &Wl[(64 * wg + 16 * t + m) * 136 + 32 * s + 8 * quad]);
      c = __builtin_amdgcn_mfma_f32_16x16x32_bf16(a[s], bf, c, 0, 0, 0);
    }
    int co = 64 * wg + 16 * t + m;
#pragma unroll
    for (int r = 0; r < 4; ++r) {
      float v = c[r] > 0.f ? c[r] : 0.f;  // ReLU
      He[(nrow + r) * 144 + co] = f2bf(v);
    }
  }
  __syncthreads();

  // ---- phase-2 coordinates + ei register prefetch (hides ei HBM latency
  //      under the h store; deposited into LDS after He reads complete) ----
  const int s4    = tid >> 9;            // unit 0/1
  const int t2    = tid & 511;
  const int rest2 = slot + 64 * s4;      // 0..127: unit id within group
  const int b2    = (j << 1) | (rest2 >> 6);
  const int n02   = (rest2 & 63) * 64;
  i32x4 eiv = {0, 0, 0, 0};
  if (t2 < 256)
    eiv = __builtin_nontemporal_load(
        reinterpret_cast<const i32x4*>(ei + ((size_t)b2 * N_ + n02 + (t2 >> 2)) * K_) +
        (t2 & 3));

  {  // vectorized h store: 2 x dwordx4/thread, 1 KB contiguous per wave
    unsigned short* hb = h + ((size_t)b * N_ + n0) * COUT_;
    const int seg = tid & 15;
    const int nr  = tid >> 4;   // 0..63
#pragma unroll
    for (int p = 0; p < 2; ++p) {
      int n = nr + 64 * p;
      uint4 v = *reinterpret_cast<const uint4*>(&He[n * 144 + 8 * seg]);
      *reinterpret_cast<uint4*>(hb + (size_t)n * COUT_ + 8 * seg) = v;
    }
  }
  __syncthreads();   // h stores drained (vmcnt 0) + He reads done

  // deposit neighbor indices into He-alias: per unit [17][64], k=16 self loop
  int* idxs = reinterpret_cast<int*>(He) + s4 * (17 * 64);
  if (t2 < 256) {
    int n  = t2 >> 2;        // 0..63
    int kq = t2 & 3;
    idxs[(4 * kq + 0) * 64 + n] = eiv.x;
    idxs[(4 * kq + 1) * 64 + n] = eiv.y;
    idxs[(4 * kq + 2) * 64 + n] = eiv.z;
    idxs[(4 * kq + 3) * 64 + n] = eiv.w;
  }
  if (t2 < 64) idxs[16 * 64 + t2] = n02 + t2;

  // ---- per-group barrier (64 blocks sharing j; produce AND consume h[2j..]).
  //      RELEASE fetch_add: L2 writeback (lines stay valid-clean) => same-XCD
  //      gathers hit L2; cross-XCD correctness via L3 visibility point.
  if (tid == 0) {
    int* cnt = &g_bar[j * 32];
    int base = __hip_atomic_fetch_add(cnt, 1, __ATOMIC_RELEASE,
                                      __HIP_MEMORY_SCOPE_AGENT);
    int target = (base & ~63) + 64;   // end of this launch's epoch
    while (__hip_atomic_load(cnt, __ATOMIC_RELAXED,
                             __HIP_MEMORY_SCOPE_AGENT) < target)
      __builtin_amdgcn_s_sleep(4);
  }
  __syncthreads();

  // ================= phase 2: gather + mean + bias =================
  const int q = t2 & 15;   // co = 8q..8q+7 (16 lanes = one 256 B h row)
  const int g = t2 >> 4;   // 0..31 -> n_local = 2g, 2g+1
  const unsigned short* hb2 = h + (size_t)b2 * N_ * COUT_;

  float acc[2][8];
#pragma unroll
  for (int jj = 0; jj < 2; ++jj)
#pragma unroll
    for (int c = 0; c < 8; ++c) acc[jj][c] = 0.f;

#pragma unroll 2
  for (int k = 0; k < 17; ++k) {
    uint4 v[2];
#pragma unroll
    for (int jj = 0; jj < 2; ++jj) {
      int node = idxs[k * 64 + 2 * g + jj];
      v[jj] = *reinterpret_cast<const uint4*>(hb2 + (size_t)node * COUT_ + 8 * q);
    }
#pragma unroll
    for (int jj = 0; jj < 2; ++jj) {
      acc[jj][0] += __uint_as_float(v[jj].x << 16);
      acc[jj][1] += __uint_as_float(v[jj].x & 0xffff0000u);
      acc[jj][2] += __uint_as_float(v[jj].y << 16);
      acc[jj][3] += __uint_as_float(v[jj].y & 0xffff0000u);
      acc[jj][4] += __uint_as_float(v[jj].z << 16);
      acc[jj][5] += __uint_as_float(v[jj].z & 0xffff0000u);
      acc[jj][6] += __uint_as_float(v[jj].w << 16);
      acc[jj][7] += __uint_as_float(v[jj].w & 0xffff0000u);
    }
  }

  const float norm = 1.0f / 17.0f;
  const float4 bv0 = *reinterpret_cast<const float4*>(bias + 8 * q);
  const float4 bv1 = *reinterpret_cast<const float4*>(bias + 8 * q + 4);
  float* ob = out + (size_t)b2 * COUT_ * N_ + n02 + 2 * g;
#pragma unroll
  for (int c = 0; c < 8; ++c) {
    int co = 8 * q + c;
    float bb = (c < 4) ? ((c == 0) ? bv0.x : (c == 1) ? bv0.y : (c == 2) ? bv0.z : bv0.w)
                       : ((c == 4) ? bv1.x : (c == 5) ? bv1.y : (c == 6) ? bv1.z : bv1.w);
    float2 r;
    r.x = acc[0][c] * norm + bb;
    r.y = acc[1][c] * norm + bb;
    *reinterpret_cast<float2*>(ob + (size_t)co * N_) = r;
  }
}

extern "C" void kernel_launch(void* const* d_in, const int* in_sizes, int n_in,
                              void* d_out, int out_size, void* d_ws, size_t ws_size,
                              hipStream_t stream) {
  const float* x    = (const float*)d_in[0];
  const int*   ei   = (const int*)d_in[1];   // [2][B][N][K]; plane 0
  const float* W    = (const float*)d_in[2];
  const float* bias = (const float*)d_in[3];
  float* out = (float*)d_out;
  unsigned short* h = (unsigned short*)d_ws;  // 16 MB

  fused_k<<<dim3(512), dim3(1024), 0, stream>>>(W, x, ei, bias, out, h);
}

// Round 3
// 134.971 us; speedup vs baseline: 1.0469x; 1.0469x over previous
//
#include <hip/hip_runtime.h>

#define B_    16
#define CIN_  128
#define COUT_ 128
#define N_    4096
#define K_    16

typedef __attribute__((ext_vector_type(8))) short bf16x8;  // 8 bf16 = 4 VGPR
typedef __attribute__((ext_vector_type(4))) float f32x4;
typedef __attribute__((ext_vector_type(4))) int   i32x4;

__device__ inline unsigned short f2bf(float f) {  // round-to-nearest-even
  unsigned u = __float_as_uint(f);
  u += 0x7fffu + ((u >> 16) & 1u);
  return (unsigned short)(u >> 16);
}

// Monotonic per-group barrier counters (group = blocks sharing l&7 = one XCD
// under round-robin dispatch). Never reset; each launch consumes one epoch of
// exactly 64 increments per group: target = (base & ~63) + 64.
__device__ int g_bar[8 * 32];

// ---------------------------------------------------------------------------
// Fused kernel: 512 blocks x 512 thr. LDS = 71680 B => exactly 2 blocks/CU;
// grid == 2*256 = capacity => all blocks co-resident => spin barrier is
// deadlock-free. launch_bounds(512,4) => 128-VGPR budget (R2's failure was
// the 64-VGPR budget of (1024,8): allocator collapsed to 28 VGPR + scratch,
// killing gather MLP). Two independent resident blocks cover each other's
// barrier drain/spin latency.
// Phase 1: 128n x 128co tile; 8 waves, each 16n x 128co (32 MFMAs/wave).
// Phase 2: 2 units x 256 thr, each the PROVEN R0 aggr shape: 64n x 128co,
//          acc[4][8], v[4] outstanding uint4 gathers.
// ---------------------------------------------------------------------------
__global__ __launch_bounds__(512, 4) void fused_k(
    const float* __restrict__ W, const float* __restrict__ x,
    const int* __restrict__ ei, const float* __restrict__ bias,
    float* __restrict__ out, unsigned short* __restrict__ h) {
  __shared__ unsigned short Wl[128 * 136];                 // [co][ci]+8 pad, 34.8 KB
  __shared__ __align__(16) unsigned short He[128 * 144];   // [n][co]+16 pad, 36.9 KB
                                                           // (aliased by idxs in ph2)
  const int tid  = threadIdx.x;
  const int l    = blockIdx.x;          // 0..511
  const int j    = l & 7;               // group / XCD under round-robin
  const int slot = l >> 3;              // 0..63
  const int b    = (j << 1) | (slot >> 5);
  const int n0   = (slot & 31) * 128;

  const int lane = tid & 63;
  const int w    = tid >> 6;            // wave 0..7 -> n slice [n0+16w, +16)
  const int m    = lane & 15;
  const int quad = lane >> 4;

  // ---- phase 0: stage W fp32 -> bf16 -> LDS (identical RTE conversion) ----
#pragma unroll
  for (int r = 0; r < 4; ++r) {
    int id  = tid + 512 * r;       // 0..2047 segments of 8 floats
    int co  = id >> 4;
    int seg = id & 15;
    const float4* wp = reinterpret_cast<const float4*>(W + co * CIN_ + 8 * seg);
    float4 v0 = wp[0];
    float4 v1 = wp[1];
    unsigned p0 = (unsigned)f2bf(v0.x) | ((unsigned)f2bf(v0.y) << 16);
    unsigned p1 = (unsigned)f2bf(v0.z) | ((unsigned)f2bf(v0.w) << 16);
    unsigned p2 = (unsigned)f2bf(v1.x) | ((unsigned)f2bf(v1.y) << 16);
    unsigned p3 = (unsigned)f2bf(v1.z) | ((unsigned)f2bf(v1.w) << 16);
    *reinterpret_cast<uint4*>(&Wl[co * 136 + 8 * seg]) =
        make_uint4(p0, p1, p2, p3);
  }

  // ---- A-fragments from global (loads overlap W staging above) ----
  const float* xb = x + (size_t)b * CIN_ * N_ + n0 + 16 * w + m;
  bf16x8 a[4];
#pragma unroll
  for (int s = 0; s < 4; ++s)
#pragma unroll
    for (int t = 0; t < 8; ++t)
      a[s][t] = (short)f2bf(xb[(size_t)(32 * s + 8 * quad + t) * N_]);

  __syncthreads();

  // ---- phase 1: MFMA gemm + ReLU, epilogue transpose through He ----
  const int nrow = 16 * w + 4 * quad;   // block-local n of c[0]
#pragma unroll
  for (int t = 0; t < 8; ++t) {   // 8 co-tiles of 16
    f32x4 c = {0.f, 0.f, 0.f, 0.f};
#pragma unroll
    for (int s = 0; s < 4; ++s) { // K = 4 x 32
      bf16x8 bf = *reinterpret_cast<const bf16x8*>(
          &Wl[(16 * t + m) * 136 + 32 * s + 8 * quad]);
      c = __builtin_amdgcn_mfma_f32_16x16x32_bf16(a[s], bf, c, 0, 0, 0);
    }
    int co = 16 * t + m;
#pragma unroll
    for (int r = 0; r < 4; ++r) {
      float v = c[r] > 0.f ? c[r] : 0.f;  // ReLU
      He[(nrow + r) * 144 + co] = f2bf(v);
    }
  }
  __syncthreads();

  // ---- phase-2 coordinates + ei register prefetch (hides ei latency
  //      under the h store; deposited into LDS after He reads complete) ----
  const int s4    = tid >> 8;            // unit 0/1
  const int t2    = tid & 255;
  const int rest2 = slot + 64 * s4;      // 0..127: unit id within group
  const int b2    = (j << 1) | (rest2 >> 6);
  const int n02   = (rest2 & 63) * 64;
  i32x4 eiv = __builtin_nontemporal_load(
      reinterpret_cast<const i32x4*>(ei + ((size_t)b2 * N_ + n02 + (t2 >> 2)) * K_) +
      (t2 & 3));

  {  // vectorized h store: 4 x dwordx4/thread; 16 lanes = one 256 B row
    unsigned short* hb = h + ((size_t)b * N_ + n0) * COUT_;
    const int seg = tid & 15;
    const int nr  = tid >> 4;   // 0..31
#pragma unroll
    for (int p = 0; p < 4; ++p) {
      int n = nr + 32 * p;
      uint4 v = *reinterpret_cast<const uint4*>(&He[n * 144 + 8 * seg]);
      *reinterpret_cast<uint4*>(hb + (size_t)n * COUT_ + 8 * seg) = v;
    }
  }
  __syncthreads();   // h stores drained (vmcnt 0) + He reads done

  // deposit neighbor indices into He-alias: per unit [17][64], k=16 self loop
  int* idxs = reinterpret_cast<int*>(He) + s4 * (17 * 64);
  {
    int n  = t2 >> 2;        // 0..63
    int kq = t2 & 3;
    idxs[(4 * kq + 0) * 64 + n] = eiv.x;
    idxs[(4 * kq + 1) * 64 + n] = eiv.y;
    idxs[(4 * kq + 2) * 64 + n] = eiv.z;
    idxs[(4 * kq + 3) * 64 + n] = eiv.w;
  }
  if (t2 < 64) idxs[16 * 64 + t2] = n02 + t2;

  // ---- per-group barrier (64 blocks sharing j; produce AND consume h[2j..]).
  //      RELEASE fetch_add: L2 writeback (lines stay valid-clean) => same-XCD
  //      gathers hit L2; cross-XCD correctness via L3 visibility point.
  if (tid == 0) {
    int* cnt = &g_bar[j * 32];
    int base = __hip_atomic_fetch_add(cnt, 1, __ATOMIC_RELEASE,
                                      __HIP_MEMORY_SCOPE_AGENT);
    int target = (base & ~63) + 64;   // end of this launch's epoch
    while (__hip_atomic_load(cnt, __ATOMIC_RELAXED,
                             __HIP_MEMORY_SCOPE_AGENT) < target)
      __builtin_amdgcn_s_sleep(2);
  }
  __syncthreads();

  // ================= phase 2: gather + mean + bias =================
  // Per 256-thr unit: EXACT R0-proven shape (64n x 128co, acc[4][8], v[4]).
  const int q = t2 & 15;   // co = 8q..8q+7 (16 lanes = one 256 B h row)
  const int g = t2 >> 4;   // 0..15 -> n_local = 4g .. 4g+3
  const unsigned short* hb2 = h + (size_t)b2 * N_ * COUT_;

  float acc[4][8];
#pragma unroll
  for (int jj = 0; jj < 4; ++jj)
#pragma unroll
    for (int c = 0; c < 8; ++c) acc[jj][c] = 0.f;

#pragma unroll 2
  for (int k = 0; k < 17; ++k) {
    uint4 v[4];
#pragma unroll
    for (int jj = 0; jj < 4; ++jj) {
      int node = idxs[k * 64 + 4 * g + jj];
      v[jj] = *reinterpret_cast<const uint4*>(hb2 + (size_t)node * COUT_ + 8 * q);
    }
#pragma unroll
    for (int jj = 0; jj < 4; ++jj) {
      acc[jj][0] += __uint_as_float(v[jj].x << 16);
      acc[jj][1] += __uint_as_float(v[jj].x & 0xffff0000u);
      acc[jj][2] += __uint_as_float(v[jj].y << 16);
      acc[jj][3] += __uint_as_float(v[jj].y & 0xffff0000u);
      acc[jj][4] += __uint_as_float(v[jj].z << 16);
      acc[jj][5] += __uint_as_float(v[jj].z & 0xffff0000u);
      acc[jj][6] += __uint_as_float(v[jj].w << 16);
      acc[jj][7] += __uint_as_float(v[jj].w & 0xffff0000u);
    }
  }

  const float norm = 1.0f / 17.0f;
  const float4 bv0 = *reinterpret_cast<const float4*>(bias + 8 * q);
  const float4 bv1 = *reinterpret_cast<const float4*>(bias + 8 * q + 4);
  float* ob = out + (size_t)b2 * COUT_ * N_ + n02 + 4 * g;
#pragma unroll
  for (int c = 0; c < 8; ++c) {
    int co = 8 * q + c;
    float bb = (c < 4) ? ((c == 0) ? bv0.x : (c == 1) ? bv0.y : (c == 2) ? bv0.z : bv0.w)
                       : ((c == 4) ? bv1.x : (c == 5) ? bv1.y : (c == 6) ? bv1.z : bv1.w);
    float4 r;
    r.x = acc[0][c] * norm + bb;
    r.y = acc[1][c] * norm + bb;
    r.z = acc[2][c] * norm + bb;
    r.w = acc[3][c] * norm + bb;
    *reinterpret_cast<float4*>(ob + (size_t)co * N_) = r;  // 16B, 64B/segment
  }
}

extern "C" void kernel_launch(void* const* d_in, const int* in_sizes, int n_in,
                              void* d_out, int out_size, void* d_ws, size_t ws_size,
                              hipStream_t stream) {
  const float* x    = (const float*)d_in[0];
  const int*   ei   = (const int*)d_in[1];   // [2][B][N][K]; plane 0
  const float* W    = (const float*)d_in[2];
  const float* bias = (const float*)d_in[3];
  float* out = (float*)d_out;
  unsigned short* h = (unsigned short*)d_ws;  // 16 MB

  fused_k<<<dim3(512), dim3(512), 0, stream>>>(W, x, ei, bias, out, h);
}

// Round 4
// 112.556 us; speedup vs baseline: 1.2554x; 1.1992x over previous
//
#include <hip/hip_runtime.h>

#define B_    16
#define CIN_  128
#define COUT_ 128
#define N_    4096
#define K_    16

typedef __attribute__((ext_vector_type(8))) short bf16x8;  // 8 bf16 = 4 VGPR
typedef __attribute__((ext_vector_type(4))) float f32x4;
typedef __attribute__((ext_vector_type(4))) int   i32x4;

__device__ inline unsigned short f2bf(float f) {  // round-to-nearest-even
  unsigned u = __float_as_uint(f);
  u += 0x7fffu + ((u >> 16) & 1u);
  return (unsigned short)(u >> 16);
}

// ---------------------------------------------------------------------------
// REVERT to the proven R0 split pipeline (112.65 us baseline), with the one
// verified-positive piece of the fusion experiments folded in: W fp32->bf16
// conversion happens inside gemm's LDS staging (removes the convW dispatch +
// its dependency stall; conversion overlaps the x-fragment HBM loads).
// Fusion post-mortem (R1-R3): single-kernel variants proved gathers hit L2
// (FETCH ~28 MB, no gather HBM traffic) yet ran 45-58 us vs split's ~37.6 us
// in-kernel -- the group-barrier tail + lockstep phases at reduced occupancy
// cost more than the L2-residency win. Split aggr already gets L2 reuse via
// the shared XCD-affinity mapping (h slab fetched L3->L2 once, reused ~17x).
//
// XCD-affinity: dispatch is round-robin over 8 XCDs by linear block id, so
// batch b is pinned to XCD b>>1 in BOTH kernels -> gemm produces h[b] into
// the same XCD whose L2/L3 path aggr gathers from.
// ---------------------------------------------------------------------------
// Kernel 1: h[b][n][co] = bf16(relu(sum_ci W[co][ci]*x[b][ci][n]))
// 256 blocks x 1024 thr (1 block/CU, 16 waves); tile 256n x 128co.
// ---------------------------------------------------------------------------
__global__ __launch_bounds__(1024, 4) void gemm_relu_k(
    const float* __restrict__ W, const float* __restrict__ x,
    unsigned short* __restrict__ h) {
  __shared__ unsigned short Wl[128 * 136];   // [co][ci], +8 pad (34.8 KB)
  __shared__ unsigned short He[256 * 144];   // [n][co], +16 pad (73.7 KB)
  const int tid  = threadIdx.x;
  const int l    = blockIdx.x;          // 0..255
  const int slot = l >> 3;              // 0..31
  const int b    = ((l & 7) << 1) | (slot >> 4);
  const int n0   = (slot & 15) * 256;

  // ---- stage W fp32 -> bf16 -> LDS (2 x 8-float segments per thread;
  //      identical RTE conversion to the old convW_k; W reads are 64 KB
  //      broadcast, L2/L3-cached -- verified no FETCH blowup in R1-R3) ----
#pragma unroll
  for (int r = 0; r < 2; ++r) {
    int id  = tid + 1024 * r;   // 0..2047 segments of 8 floats
    int co  = id >> 4;          // 0..127
    int seg = id & 15;          // 8-bf16 segment along ci
    const float4* wp = reinterpret_cast<const float4*>(W + co * CIN_ + 8 * seg);
    float4 v0 = wp[0];
    float4 v1 = wp[1];
    unsigned p0 = (unsigned)f2bf(v0.x) | ((unsigned)f2bf(v0.y) << 16);
    unsigned p1 = (unsigned)f2bf(v0.z) | ((unsigned)f2bf(v0.w) << 16);
    unsigned p2 = (unsigned)f2bf(v1.x) | ((unsigned)f2bf(v1.y) << 16);
    unsigned p3 = (unsigned)f2bf(v1.z) | ((unsigned)f2bf(v1.w) << 16);
    *reinterpret_cast<uint4*>(&Wl[co * 136 + 8 * seg]) =
        make_uint4(p0, p1, p2, p3);
  }

  const int lane = tid & 63;
  const int w    = tid >> 6;    // wave 0..15 -> n slice [n0+16w, +16)
  const int m    = lane & 15;
  const int quad = lane >> 4;

  // ---- A-fragments straight from global (overlap the W staging above) ----
  const float* xb = x + (size_t)b * CIN_ * N_ + n0 + 16 * w + m;
  bf16x8 a[4];
#pragma unroll
  for (int s = 0; s < 4; ++s)
#pragma unroll
    for (int j = 0; j < 8; ++j)
      a[s][j] = (short)f2bf(xb[(size_t)(32 * s + 8 * quad + j) * N_]);

  __syncthreads();

  const int nrow = 16 * w + 4 * quad;   // block-local n of c[0]
#pragma unroll
  for (int t = 0; t < 8; ++t) {   // 8 co-tiles of 16
    f32x4 c = {0.f, 0.f, 0.f, 0.f};
#pragma unroll
    for (int s = 0; s < 4; ++s) { // K = 4 x 32
      bf16x8 bf = *reinterpret_cast<const bf16x8*>(
          &Wl[(16 * t + m) * 136 + 32 * s + 8 * quad]);
      c = __builtin_amdgcn_mfma_f32_16x16x32_bf16(a[s], bf, c, 0, 0, 0);
    }
    int co = 16 * t + m;
#pragma unroll
    for (int r = 0; r < 4; ++r) {
      float v = c[r] > 0.f ? c[r] : 0.f;  // ReLU
      He[(nrow + r) * 144 + co] = f2bf(v);  // pad 144: quads hit distinct banks
    }
  }
  __syncthreads();

  // ---- vectorized store: 4 x dwordx4/thread, 1 KB contiguous per wave ----
  unsigned short* hb = h + ((size_t)b * N_ + n0) * COUT_;
  const int seg = tid & 15;
  const int nr  = tid >> 4;   // 0..63
#pragma unroll
  for (int p = 0; p < 4; ++p) {
    int n = nr + 64 * p;
    uint4 v = *reinterpret_cast<const uint4*>(&He[n * 144 + 8 * seg]);
    *reinterpret_cast<uint4*>(hb + (size_t)n * COUT_ + 8 * seg) = v;
  }
}

// ---------------------------------------------------------------------------
// Kernel 2: out[b][co][n] = (sum_{17} h[b][idx'][:])/17 + bias, idx' incl self
// EXACT R0 configuration (best measured): 1024 blocks x 256 thr; tile
// 64n x 128co; q=tid&15 -> 8 co (16B gather: 16 lanes = one 256B h row),
// g=tid>>4 -> 4 n; unroll-2 over k; launch_bounds(256,4) -> no spill.
// ---------------------------------------------------------------------------
__global__ __launch_bounds__(256, 4) void aggr_k(
    const unsigned short* __restrict__ h, const int* __restrict__ ei,
    const float* __restrict__ bias, float* __restrict__ out) {
  __shared__ int idx_t[17 * 64];  // [k][n], k=16 is the self loop
  const int tid  = threadIdx.x;
  const int l    = blockIdx.x;
  const int rest = l >> 3;                        // 0..127
  const int b    = ((l & 7) << 1) | (rest >> 6);
  const int n0   = (rest & 63) * 64;

  {  // stage+transpose neighbor indices (coalesced int4, NT to spare L2)
    int n  = tid >> 2;       // 0..63
    int kq = tid & 3;        // int4 along k
    i32x4 v = __builtin_nontemporal_load(
        reinterpret_cast<const i32x4*>(ei + ((size_t)b * N_ + n0 + n) * K_) + kq);
    idx_t[(4 * kq + 0) * 64 + n] = v.x;
    idx_t[(4 * kq + 1) * 64 + n] = v.y;
    idx_t[(4 * kq + 2) * 64 + n] = v.z;
    idx_t[(4 * kq + 3) * 64 + n] = v.w;
    if (tid < 64) idx_t[16 * 64 + tid] = n0 + tid;  // self loop
  }
  __syncthreads();

  const int q = tid & 15;   // co = 8q..8q+7
  const int g = tid >> 4;   // n_local = 4g .. 4g+3
  const unsigned short* hb = h + (size_t)b * N_ * COUT_;

  float acc[4][8];
#pragma unroll
  for (int j = 0; j < 4; ++j)
#pragma unroll
    for (int c = 0; c < 8; ++c) acc[j][c] = 0.f;

#pragma unroll 2
  for (int k = 0; k < 17; ++k) {
    uint4 v[4];
#pragma unroll
    for (int j = 0; j < 4; ++j) {
      int node = idx_t[k * 64 + 4 * g + j];
      v[j] = *reinterpret_cast<const uint4*>(hb + (size_t)node * COUT_ + 8 * q);
    }
#pragma unroll
    for (int j = 0; j < 4; ++j) {
      acc[j][0] += __uint_as_float(v[j].x << 16);
      acc[j][1] += __uint_as_float(v[j].x & 0xffff0000u);
      acc[j][2] += __uint_as_float(v[j].y << 16);
      acc[j][3] += __uint_as_float(v[j].y & 0xffff0000u);
      acc[j][4] += __uint_as_float(v[j].z << 16);
      acc[j][5] += __uint_as_float(v[j].z & 0xffff0000u);
      acc[j][6] += __uint_as_float(v[j].w << 16);
      acc[j][7] += __uint_as_float(v[j].w & 0xffff0000u);
    }
  }

  const float norm = 1.0f / 17.0f;
  const float4 bv0 = *reinterpret_cast<const float4*>(bias + 8 * q);
  const float4 bv1 = *reinterpret_cast<const float4*>(bias + 8 * q + 4);
  float* ob = out + (size_t)b * COUT_ * N_ + n0 + 4 * g;
#pragma unroll
  for (int c = 0; c < 8; ++c) {
    int co = 8 * q + c;
    float bb = (c < 4) ? ((c == 0) ? bv0.x : (c == 1) ? bv0.y : (c == 2) ? bv0.z : bv0.w)
                       : ((c == 4) ? bv1.x : (c == 5) ? bv1.y : (c == 6) ? bv1.z : bv1.w);
    float4 r;
    r.x = acc[0][c] * norm + bb;
    r.y = acc[1][c] * norm + bb;
    r.z = acc[2][c] * norm + bb;
    r.w = acc[3][c] * norm + bb;
    *reinterpret_cast<float4*>(ob + (size_t)co * N_) = r;  // 16B, 64B/segment
  }
}

extern "C" void kernel_launch(void* const* d_in, const int* in_sizes, int n_in,
                              void* d_out, int out_size, void* d_ws, size_t ws_size,
                              hipStream_t stream) {
  const float* x    = (const float*)d_in[0];
  const int*   ei   = (const int*)d_in[1];   // [2][B][N][K]; plane 0
  const float* W    = (const float*)d_in[2];
  const float* bias = (const float*)d_in[3];
  float* out = (float*)d_out;
  unsigned short* h = (unsigned short*)d_ws;  // 16 MB

  gemm_relu_k<<<dim3(256), dim3(1024), 0, stream>>>(W, x, h);
  aggr_k<<<dim3(B_ * N_ / 64), 256, 0, stream>>>(h, ei, bias, out);
}